// Round 3
// baseline (760.598 us; speedup 1.0000x reference)
//
#include <hip/hip_runtime.h>

// ---------- types ----------
typedef __attribute__((ext_vector_type(8))) short short8;    // 8 bf16 (4 VGPRs)
typedef __attribute__((ext_vector_type(4))) float floatx4;   // MFMA acc

// fp32 -> bf16 (RNE)
static __device__ __forceinline__ unsigned short f2bf(float f) {
    unsigned int u = __float_as_uint(f);
    u = (u + 0x7FFFu + ((u >> 16) & 1u)) >> 16;
    return (unsigned short)u;
}

// ---------- kernel 0: starts[c] = lower_bound(segment_ids, c), c in [0, num_cells] ----------
__global__ void starts_kernel(const int* __restrict__ seg, int M, int num_cells,
                              int* __restrict__ starts) {
    int m = blockIdx.x * blockDim.x + threadIdx.x;
    if (m > M) return;
    int prev = (m == 0) ? -1 : seg[m - 1];
    int cur  = (m == M) ? num_cells : seg[m];
    for (int c = prev + 1; c <= cur; ++c) starts[c] = m;
}

// ---------- kernel 1: W (256x512 f32) -> Wt (512x256 bf16) ----------
__global__ void prep_wt_kernel(const float* __restrict__ W,
                               unsigned short* __restrict__ Wt) {
    int g = blockIdx.x * blockDim.x + threadIdx.x;   // 0 .. 512*256-1
    int n = g >> 8;          // 0..511
    int k = g & 255;         // 0..255
    Wt[g] = f2bf(W[k * 512 + n]);
}

// ---------- kernel 2: segment mean -> cell_emb bf16 [Mpad][256] ----------
// member-parallel: block owns 16 cells (16 KB LDS fp32 accum); 4 waves iterate
// the block's contiguous member range; SoA lane->feature mapping makes the
// 4 ds_add_f32 per member conflict-free.
#define CPB 16
__global__ __launch_bounds__(256) void seg_mean_kernel(
        const float* __restrict__ chunk_features,
        const int* __restrict__ member_idx,
        const int* __restrict__ segment_ids,
        const int* __restrict__ starts,
        int num_cells,
        unsigned short* __restrict__ cell_emb) {
    __shared__ float accs[CPB * 256];

    const int tid  = threadIdx.x;
    const int wid  = tid >> 6;
    const int lane = tid & 63;
    const int c0 = blockIdx.x * CPB;

#pragma unroll
    for (int i = 0; i < CPB; ++i)
        accs[tid + i * 256] = 0.f;
    __syncthreads();

    if (c0 < num_cells) {
        int cend = c0 + CPB; if (cend > num_cells) cend = num_cells;
        const int s = starts[c0];
        const int e = starts[cend];

        int m = s + wid;
        if (m < e) {
            int mu  = __builtin_amdgcn_readfirstlane(m);
            int idx = member_idx[mu];
            int cl  = segment_ids[mu] - c0;
            while (true) {
                int mn = m + 4;
                bool more = mn < e;
                int idx2 = 0, cl2 = 0;
                if (more) {
                    int mu2 = __builtin_amdgcn_readfirstlane(mn);
                    idx2 = member_idx[mu2];
                    cl2  = segment_ids[mu2] - c0;
                }
                const float* row = chunk_features + (size_t)idx * 256;
                float v0 = row[lane];
                float v1 = row[lane + 64];
                float v2 = row[lane + 128];
                float v3 = row[lane + 192];
                float* a = accs + cl * 256;
                atomicAdd(a + lane,       v0);
                atomicAdd(a + lane + 64,  v1);
                atomicAdd(a + lane + 128, v2);
                atomicAdd(a + lane + 192, v3);
                if (!more) break;
                m = mn; idx = idx2; cl = cl2;
            }
        }
    }
    __syncthreads();

    // epilogue: wave w -> local cells w, w+4, w+8, w+12
#pragma unroll
    for (int i = 0; i < CPB / 4; ++i) {
        int cl = wid + i * 4;
        int c  = c0 + cl;
        float4 v = *(float4*)(accs + cl * 256 + lane * 4);
        float inv = 0.f;
        if (c < num_cells) {
            int cnt = starts[c + 1] - starts[c];
            inv = 1.0f / (float)(cnt > 0 ? cnt : 1);
        }
        ushort4 o;
        o.x = f2bf(v.x * inv);
        o.y = f2bf(v.y * inv);
        o.z = f2bf(v.z * inv);
        o.w = f2bf(v.w * inv);
        *(ushort4*)(cell_emb + (size_t)c * 256 + lane * 4) = o;
    }
}

// ---------- kernel 3: C[Mpad x 512] = A[Mpad x 256] * W[256 x 512] + b ----------
// A bf16 row-major, Bt = W^T bf16 row-major [512][256].
// 128x128 block tile, 4 waves (2x2), 64x64 wave tile, BK=32, 16x16x32 MFMA.
__global__ __launch_bounds__(256) void gemm_kernel(
        const unsigned short* __restrict__ A,
        const unsigned short* __restrict__ Bt,
        const float* __restrict__ bias,
        float* __restrict__ out,
        int Mreal) {
    constexpr int LDSS = 40;             // padded stride (bf16 elems) to spread banks
    __shared__ unsigned short As[128 * LDSS];
    __shared__ unsigned short Bs[128 * LDSS];

    const int tid  = threadIdx.x;
    const int wid  = tid >> 6;
    const int lane = tid & 63;
    const int wm = wid & 1, wn = wid >> 1;
    const int l15 = lane & 15, q = lane >> 4;
    const int m0 = blockIdx.y * 128;
    const int n0 = blockIdx.x * 128;

    floatx4 acc[4][4] = {};

    for (int kb = 0; kb < 256; kb += 32) {
#pragma unroll
        for (int r = 0; r < 2; ++r) {
            int chunk = tid + r * 256;          // 0..511
            int row = chunk >> 2;               // 0..127
            int col = (chunk & 3) * 8;          // 0,8,16,24
            *(short8*)&As[row * LDSS + col] =
                *(const short8*)&A[(size_t)(m0 + row) * 256 + kb + col];
            *(short8*)&Bs[row * LDSS + col] =
                *(const short8*)&Bt[(size_t)(n0 + row) * 256 + kb + col];
        }
        __syncthreads();

        short8 af[4], bf[4];
#pragma unroll
        for (int mi = 0; mi < 4; ++mi)
            af[mi] = *(const short8*)&As[(wm * 64 + mi * 16 + l15) * LDSS + q * 8];
#pragma unroll
        for (int ni = 0; ni < 4; ++ni)
            bf[ni] = *(const short8*)&Bs[(wn * 64 + ni * 16 + l15) * LDSS + q * 8];
#pragma unroll
        for (int mi = 0; mi < 4; ++mi)
#pragma unroll
            for (int ni = 0; ni < 4; ++ni)
                acc[mi][ni] = __builtin_amdgcn_mfma_f32_16x16x32_bf16(
                    af[mi], bf[ni], acc[mi][ni], 0, 0, 0);
        __syncthreads();
    }

#pragma unroll
    for (int ni = 0; ni < 4; ++ni) {
        int n = n0 + wn * 64 + ni * 16 + l15;
        float bv = bias[n];
#pragma unroll
        for (int mi = 0; mi < 4; ++mi) {
            int mbase = m0 + wm * 64 + mi * 16 + q * 4;
#pragma unroll
            for (int r = 0; r < 4; ++r) {
                int row = mbase + r;
                if (row < Mreal)
                    out[(size_t)row * 512 + n] = acc[mi][ni][r] + bv;
            }
        }
    }
}

extern "C" void kernel_launch(void* const* d_in, const int* in_sizes, int n_in,
                              void* d_out, int out_size, void* d_ws, size_t ws_size,
                              hipStream_t stream) {
    const float* chunk_features = (const float*)d_in[0];
    const int*   member_idx     = (const int*)d_in[1];
    const int*   segment_ids    = (const int*)d_in[2];
    const float* W              = (const float*)d_in[4];
    const float* bias           = (const float*)d_in[5];
    float* out = (float*)d_out;

    const int M        = in_sizes[1];            // 400000 members
    const int out_dim  = in_sizes[5];            // 512
    const int num_cells = out_size / out_dim;    // 50000
    const int mtiles = (num_cells + 127) / 128;  // 391
    const int Mpad   = mtiles * 128;             // 50048

    unsigned short* cell_emb = (unsigned short*)d_ws;                 // Mpad*256 bf16
    unsigned short* Wt       = cell_emb + (size_t)Mpad * 256;         // 512*256 bf16
    int*            starts   = (int*)(Wt + 512 * 256);                // num_cells+1 ints

    hipLaunchKernelGGL(starts_kernel, dim3((M + 1 + 255) / 256), dim3(256), 0, stream,
                       segment_ids, M, num_cells, starts);
    hipLaunchKernelGGL(prep_wt_kernel, dim3(512), dim3(256), 0, stream, W, Wt);
    hipLaunchKernelGGL(seg_mean_kernel, dim3(Mpad / CPB), dim3(256), 0, stream,
                       chunk_features, member_idx, segment_ids, starts, num_cells, cell_emb);
    hipLaunchKernelGGL(gemm_kernel, dim3(4, mtiles), dim3(256), 0, stream,
                       cell_emb, Wt, bias, out, num_cells);
}

// Round 4
// 282.379 us; speedup vs baseline: 2.6935x; 2.6935x over previous
//
#include <hip/hip_runtime.h>

// ---------- types ----------
typedef __attribute__((ext_vector_type(8))) short short8;    // 8 bf16 (4 VGPRs)
typedef __attribute__((ext_vector_type(4))) float floatx4;   // MFMA acc

// fp32 -> bf16 (RNE)
static __device__ __forceinline__ unsigned short f2bf(float f) {
    unsigned int u = __float_as_uint(f);
    u = (u + 0x7FFFu + ((u >> 16) & 1u)) >> 16;
    return (unsigned short)u;
}

// ---------- kernel 0: starts[c] = lower_bound(segment_ids, c), c in [0, num_cells] ----------
__global__ void starts_kernel(const int* __restrict__ seg, int M, int num_cells,
                              int* __restrict__ starts) {
    int m = blockIdx.x * blockDim.x + threadIdx.x;
    if (m > M) return;
    int prev = (m == 0) ? -1 : seg[m - 1];
    int cur  = (m == M) ? num_cells : seg[m];
    for (int c = prev + 1; c <= cur; ++c) starts[c] = m;
}

// ---------- kernel 1: W (256x512 f32) -> Wt (512x256 bf16) ----------
__global__ void prep_wt_kernel(const float* __restrict__ W,
                               unsigned short* __restrict__ Wt) {
    int g = blockIdx.x * blockDim.x + threadIdx.x;   // 0 .. 512*256-1
    int n = g >> 8;          // 0..511
    int k = g & 255;         // 0..255
    Wt[g] = f2bf(W[k * 512 + n]);
}

// ---------- kernel 2: segment mean -> cell_emb bf16 [Mpad][256] ----------
// wave-per-cell, NO atomics. Indices fetched coalesced once, then all row
// loads of a batch of 8 members issued before any accumulate (deep MLP:
// 8 x 256B in flight per wave; compiler drains with staged vmcnt).
__global__ __launch_bounds__(256) void seg_mean_kernel(
        const float* __restrict__ chunk_features,
        const int* __restrict__ member_idx,
        const int* __restrict__ starts,
        int num_cells,
        unsigned short* __restrict__ cell_emb) {
    const int wid  = threadIdx.x >> 6;
    const int lane = threadIdx.x & 63;
    const int c = blockIdx.x * 4 + wid;

    float4 acc = make_float4(0.f, 0.f, 0.f, 0.f);
    int cnt = 0;

    if (c < num_cells) {
        const int s = starts[c];
        const int e = starts[c + 1];
        cnt = e - s;
        const float4* cf = (const float4*)chunk_features;   // rows of 64 float4

        for (int base = s; base < e; base += 64) {
            int m = base + lane;
            int idx = (m < e) ? member_idx[m] : 0;          // coalesced
            int n = e - base; if (n > 64) n = 64;
            for (int j0 = 0; j0 < n; j0 += 8) {
                int k = n - j0; if (k > 8) k = 8;
                float4 v[8];
                // issue all loads of the batch first (independent)
#pragma unroll
                for (int j = 0; j < 8; ++j) {
                    if (j < k) {
                        int ci = __shfl(idx, j0 + j);
                        v[j] = cf[(size_t)ci * 64 + lane];
                    }
                }
                // then accumulate (compiler interleaves waitcnts vmcnt(7..0))
#pragma unroll
                for (int j = 0; j < 8; ++j) {
                    if (j < k) {
                        acc.x += v[j].x; acc.y += v[j].y;
                        acc.z += v[j].z; acc.w += v[j].w;
                    }
                }
            }
        }
    }

    float inv = 1.0f / (float)(cnt > 0 ? cnt : 1);
    ushort4 o;
    o.x = f2bf(acc.x * inv);
    o.y = f2bf(acc.y * inv);
    o.z = f2bf(acc.z * inv);
    o.w = f2bf(acc.w * inv);
    *(ushort4*)(cell_emb + (size_t)c * 256 + lane * 4) = o;
}

// ---------- kernel 3: C[Mpad x 512] = A[Mpad x 256] * W[256 x 512] + b ----------
// A bf16 row-major, Bt = W^T bf16 row-major [512][256].
// 128x128 block tile, 4 waves (2x2), 64x64 wave tile, BK=32, 16x16x32 MFMA.
__global__ __launch_bounds__(256) void gemm_kernel(
        const unsigned short* __restrict__ A,
        const unsigned short* __restrict__ Bt,
        const float* __restrict__ bias,
        float* __restrict__ out,
        int Mreal) {
    constexpr int LDSS = 40;             // padded stride (bf16 elems) to spread banks
    __shared__ unsigned short As[128 * LDSS];
    __shared__ unsigned short Bs[128 * LDSS];

    const int tid  = threadIdx.x;
    const int wid  = tid >> 6;
    const int lane = tid & 63;
    const int wm = wid & 1, wn = wid >> 1;
    const int l15 = lane & 15, q = lane >> 4;
    const int m0 = blockIdx.y * 128;
    const int n0 = blockIdx.x * 128;

    floatx4 acc[4][4] = {};

    for (int kb = 0; kb < 256; kb += 32) {
#pragma unroll
        for (int r = 0; r < 2; ++r) {
            int chunk = tid + r * 256;          // 0..511
            int row = chunk >> 2;               // 0..127
            int col = (chunk & 3) * 8;          // 0,8,16,24
            *(short8*)&As[row * LDSS + col] =
                *(const short8*)&A[(size_t)(m0 + row) * 256 + kb + col];
            *(short8*)&Bs[row * LDSS + col] =
                *(const short8*)&Bt[(size_t)(n0 + row) * 256 + kb + col];
        }
        __syncthreads();

        short8 af[4], bf[4];
#pragma unroll
        for (int mi = 0; mi < 4; ++mi)
            af[mi] = *(const short8*)&As[(wm * 64 + mi * 16 + l15) * LDSS + q * 8];
#pragma unroll
        for (int ni = 0; ni < 4; ++ni)
            bf[ni] = *(const short8*)&Bs[(wn * 64 + ni * 16 + l15) * LDSS + q * 8];
#pragma unroll
        for (int mi = 0; mi < 4; ++mi)
#pragma unroll
            for (int ni = 0; ni < 4; ++ni)
                acc[mi][ni] = __builtin_amdgcn_mfma_f32_16x16x32_bf16(
                    af[mi], bf[ni], acc[mi][ni], 0, 0, 0);
        __syncthreads();
    }

#pragma unroll
    for (int ni = 0; ni < 4; ++ni) {
        int n = n0 + wn * 64 + ni * 16 + l15;
        float bv = bias[n];
#pragma unroll
        for (int mi = 0; mi < 4; ++mi) {
            int mbase = m0 + wm * 64 + mi * 16 + q * 4;
#pragma unroll
            for (int r = 0; r < 4; ++r) {
                int row = mbase + r;
                if (row < Mreal)
                    out[(size_t)row * 512 + n] = acc[mi][ni][r] + bv;
            }
        }
    }
}

extern "C" void kernel_launch(void* const* d_in, const int* in_sizes, int n_in,
                              void* d_out, int out_size, void* d_ws, size_t ws_size,
                              hipStream_t stream) {
    const float* chunk_features = (const float*)d_in[0];
    const int*   member_idx     = (const int*)d_in[1];
    const int*   segment_ids    = (const int*)d_in[2];
    const float* W              = (const float*)d_in[4];
    const float* bias           = (const float*)d_in[5];
    float* out = (float*)d_out;

    const int M        = in_sizes[1];            // 400000 members
    const int out_dim  = in_sizes[5];            // 512
    const int num_cells = out_size / out_dim;    // 50000
    const int mtiles = (num_cells + 127) / 128;  // 391
    const int Mpad   = mtiles * 128;             // 50048

    unsigned short* cell_emb = (unsigned short*)d_ws;                 // Mpad*256 bf16
    unsigned short* Wt       = cell_emb + (size_t)Mpad * 256;         // 512*256 bf16
    int*            starts   = (int*)(Wt + 512 * 256);                // num_cells+1 ints

    hipLaunchKernelGGL(starts_kernel, dim3((M + 1 + 255) / 256), dim3(256), 0, stream,
                       segment_ids, M, num_cells, starts);
    hipLaunchKernelGGL(prep_wt_kernel, dim3(512), dim3(256), 0, stream, W, Wt);
    hipLaunchKernelGGL(seg_mean_kernel, dim3(Mpad / 4), dim3(256), 0, stream,
                       chunk_features, member_idx, starts, num_cells, cell_emb);
    hipLaunchKernelGGL(gemm_kernel, dim3(4, mtiles), dim3(256), 0, stream,
                       cell_emb, Wt, bias, out, num_cells);
}

// Round 5
// 280.947 us; speedup vs baseline: 2.7073x; 1.0051x over previous
//
#include <hip/hip_runtime.h>

// ---------- types ----------
typedef __attribute__((ext_vector_type(8))) short short8;    // 8 bf16 (4 VGPRs)
typedef __attribute__((ext_vector_type(4))) float floatx4;   // MFMA acc

// fp32 -> bf16 (RNE)
static __device__ __forceinline__ unsigned short f2bf(float f) {
    unsigned int u = __float_as_uint(f);
    u = (u + 0x7FFFu + ((u >> 16) & 1u)) >> 16;
    return (unsigned short)u;
}
static __device__ __forceinline__ float bf2f(unsigned short h) {
    return __uint_as_float(((unsigned int)h) << 16);
}

// ---------- kernel 0 (fused prep): ----------
//  blocks [0, castB)            : cast chunk_features f32 -> bf16 table (8 elems/thread)
//  blocks [castB, castB+startB) : starts[c] = lower_bound(segment_ids, c)
//  blocks [castB+startB, ...)   : Wt[n][k] = bf16(W[k][n])
__global__ __launch_bounds__(256) void prep_kernel(
        const float* __restrict__ cf, int cast_elems,
        const int* __restrict__ seg, int M, int num_cells,
        const float* __restrict__ W,
        unsigned short* __restrict__ cf16,
        int* __restrict__ starts,
        unsigned short* __restrict__ Wt,
        int castB, int startB) {
    const int b = blockIdx.x;
    const int tid = threadIdx.x;
    if (b < castB) {
        int g = (b * 256 + tid) * 8;
        if (g + 8 <= cast_elems) {
            float4 a = *(const float4*)(cf + g);
            float4 c = *(const float4*)(cf + g + 4);
            short8 o;
            o[0] = (short)f2bf(a.x); o[1] = (short)f2bf(a.y);
            o[2] = (short)f2bf(a.z); o[3] = (short)f2bf(a.w);
            o[4] = (short)f2bf(c.x); o[5] = (short)f2bf(c.y);
            o[6] = (short)f2bf(c.z); o[7] = (short)f2bf(c.w);
            *(short8*)(cf16 + g) = o;
        } else {
            for (int i = g; i < cast_elems; ++i) cf16[i] = f2bf(cf[i]);
        }
    } else if (b < castB + startB) {
        int m = (b - castB) * 256 + tid;
        if (m > M) return;
        int prev = (m == 0) ? -1 : seg[m - 1];
        int cur  = (m == M) ? num_cells : seg[m];
        for (int c = prev + 1; c <= cur; ++c) starts[c] = m;
    } else {
        int g = (b - castB - startB) * 256 + tid;   // 0 .. 512*256-1
        if (g < 512 * 256) {
            int n = g >> 8, k = g & 255;
            Wt[g] = f2bf(W[k * 512 + n]);
        }
    }
}

// ---------- kernel 1: segment mean over bf16 table -> cell_emb bf16 ----------
// wave-per-cell, no atomics. bf16 rows (512 B): lane reads ushort4 at lane*4.
// Batch-8 member loads in flight per wave; fp32 accumulation.
__global__ __launch_bounds__(256) void seg_mean_kernel(
        const unsigned short* __restrict__ cf16,
        const int* __restrict__ member_idx,
        const int* __restrict__ starts,
        int num_cells,
        unsigned short* __restrict__ cell_emb) {
    const int wid  = threadIdx.x >> 6;
    const int lane = threadIdx.x & 63;
    const int c = blockIdx.x * 4 + wid;

    float4 acc = make_float4(0.f, 0.f, 0.f, 0.f);
    int cnt = 0;

    if (c < num_cells) {
        const int s = starts[c];
        const int e = starts[c + 1];
        cnt = e - s;

        for (int base = s; base < e; base += 64) {
            int m = base + lane;
            int idx = (m < e) ? member_idx[m] : 0;          // coalesced
            int n = e - base; if (n > 64) n = 64;
            for (int j0 = 0; j0 < n; j0 += 8) {
                int k = n - j0; if (k > 8) k = 8;
                ushort4 v[8];
#pragma unroll
                for (int j = 0; j < 8; ++j) {
                    if (j < k) {
                        int ci = __shfl(idx, j0 + j);
                        v[j] = *(const ushort4*)(cf16 + (size_t)ci * 256 + lane * 4);
                    }
                }
#pragma unroll
                for (int j = 0; j < 8; ++j) {
                    if (j < k) {
                        acc.x += bf2f(v[j].x); acc.y += bf2f(v[j].y);
                        acc.z += bf2f(v[j].z); acc.w += bf2f(v[j].w);
                    }
                }
            }
        }
    }

    float inv = 1.0f / (float)(cnt > 0 ? cnt : 1);
    ushort4 o;
    o.x = f2bf(acc.x * inv);
    o.y = f2bf(acc.y * inv);
    o.z = f2bf(acc.z * inv);
    o.w = f2bf(acc.w * inv);
    *(ushort4*)(cell_emb + (size_t)c * 256 + lane * 4) = o;
}

// ---------- kernel 2: C[Mpad x 512] = A[Mpad x 256] * W[256 x 512] + b ----------
// A bf16 row-major, Bt = W^T bf16 row-major [512][256].
// 128x128 block tile, 4 waves (2x2), 64x64 wave tile, BK=32, 16x16x32 MFMA.
__global__ __launch_bounds__(256) void gemm_kernel(
        const unsigned short* __restrict__ A,
        const unsigned short* __restrict__ Bt,
        const float* __restrict__ bias,
        float* __restrict__ out,
        int Mreal) {
    constexpr int LDSS = 40;             // padded stride (bf16 elems) to spread banks
    __shared__ unsigned short As[128 * LDSS];
    __shared__ unsigned short Bs[128 * LDSS];

    const int tid  = threadIdx.x;
    const int wid  = tid >> 6;
    const int lane = tid & 63;
    const int wm = wid & 1, wn = wid >> 1;
    const int l15 = lane & 15, q = lane >> 4;
    const int m0 = blockIdx.y * 128;
    const int n0 = blockIdx.x * 128;

    floatx4 acc[4][4] = {};

    for (int kb = 0; kb < 256; kb += 32) {
#pragma unroll
        for (int r = 0; r < 2; ++r) {
            int chunk = tid + r * 256;          // 0..511
            int row = chunk >> 2;               // 0..127
            int col = (chunk & 3) * 8;          // 0,8,16,24
            *(short8*)&As[row * LDSS + col] =
                *(const short8*)&A[(size_t)(m0 + row) * 256 + kb + col];
            *(short8*)&Bs[row * LDSS + col] =
                *(const short8*)&Bt[(size_t)(n0 + row) * 256 + kb + col];
        }
        __syncthreads();

        short8 af[4], bf[4];
#pragma unroll
        for (int mi = 0; mi < 4; ++mi)
            af[mi] = *(const short8*)&As[(wm * 64 + mi * 16 + l15) * LDSS + q * 8];
#pragma unroll
        for (int ni = 0; ni < 4; ++ni)
            bf[ni] = *(const short8*)&Bs[(wn * 64 + ni * 16 + l15) * LDSS + q * 8];
#pragma unroll
        for (int mi = 0; mi < 4; ++mi)
#pragma unroll
            for (int ni = 0; ni < 4; ++ni)
                acc[mi][ni] = __builtin_amdgcn_mfma_f32_16x16x32_bf16(
                    af[mi], bf[ni], acc[mi][ni], 0, 0, 0);
        __syncthreads();
    }

#pragma unroll
    for (int ni = 0; ni < 4; ++ni) {
        int n = n0 + wn * 64 + ni * 16 + l15;
        float bv = bias[n];
#pragma unroll
        for (int mi = 0; mi < 4; ++mi) {
            int mbase = m0 + wm * 64 + mi * 16 + q * 4;
#pragma unroll
            for (int r = 0; r < 4; ++r) {
                int row = mbase + r;
                if (row < Mreal)
                    out[(size_t)row * 512 + n] = acc[mi][ni][r] + bv;
            }
        }
    }
}

extern "C" void kernel_launch(void* const* d_in, const int* in_sizes, int n_in,
                              void* d_out, int out_size, void* d_ws, size_t ws_size,
                              hipStream_t stream) {
    const float* chunk_features = (const float*)d_in[0];
    const int*   member_idx     = (const int*)d_in[1];
    const int*   segment_ids    = (const int*)d_in[2];
    const float* W              = (const float*)d_in[4];
    const float* bias           = (const float*)d_in[5];
    float* out = (float*)d_out;

    const int cast_elems = in_sizes[0];          // 100000*256 = 25.6M
    const int M          = in_sizes[1];          // 400000 members
    const int out_dim    = in_sizes[5];          // 512
    const int num_cells  = out_size / out_dim;   // 50000
    const int mtiles = (num_cells + 127) / 128;  // 391
    const int Mpad   = mtiles * 128;             // 50048

    // workspace layout (16B-aligned pieces)
    unsigned short* cell_emb = (unsigned short*)d_ws;                 // Mpad*256 bf16
    unsigned short* Wt       = cell_emb + (size_t)Mpad * 256;         // 512*256 bf16
    unsigned short* cf16     = Wt + 512 * 256;                        // cast_elems bf16
    int*            starts   = (int*)(cf16 + (((size_t)cast_elems + 7) & ~7ull)); // num_cells+1

    const int castB  = (cast_elems + 2047) / 2048;   // 8 elems/thread
    const int startB = (M + 1 + 255) / 256;
    const int wtB    = (512 * 256 + 255) / 256;

    hipLaunchKernelGGL(prep_kernel, dim3(castB + startB + wtB), dim3(256), 0, stream,
                       chunk_features, cast_elems, segment_ids, M, num_cells, W,
                       cf16, starts, Wt, castB, startB);
    hipLaunchKernelGGL(seg_mean_kernel, dim3(Mpad / 4), dim3(256), 0, stream,
                       cf16, member_idx, starts, num_cells, cell_emb);
    hipLaunchKernelGGL(gemm_kernel, dim3(4, mtiles), dim3(256), 0, stream,
                       cell_emb, Wt, bias, out, num_cells);
}

// Round 6
// 273.364 us; speedup vs baseline: 2.7824x; 1.0277x over previous
//
#include <hip/hip_runtime.h>

// ---------- types ----------
typedef __attribute__((ext_vector_type(8))) short short8;            // 8 bf16
typedef __attribute__((ext_vector_type(8))) unsigned short ushort8;  // 8 bf16
typedef __attribute__((ext_vector_type(4))) float floatx4;           // MFMA acc

// fp32 -> bf16 (RNE)
static __device__ __forceinline__ unsigned short f2bf(float f) {
    unsigned int u = __float_as_uint(f);
    u = (u + 0x7FFFu + ((u >> 16) & 1u)) >> 16;
    return (unsigned short)u;
}
static __device__ __forceinline__ float bf2f(unsigned short h) {
    return __uint_as_float(((unsigned int)h) << 16);
}

// ---------- kernel 0 (fused prep): cast table + starts + Wt ----------
__global__ __launch_bounds__(256) void prep_kernel(
        const float* __restrict__ cf, int cast_elems,
        const int* __restrict__ seg, int M, int num_cells,
        const float* __restrict__ W,
        unsigned short* __restrict__ cf16,
        int* __restrict__ starts,
        unsigned short* __restrict__ Wt,
        int castB, int startB) {
    const int b = blockIdx.x;
    const int tid = threadIdx.x;
    if (b < castB) {
        int g = (b * 256 + tid) * 8;
        if (g + 8 <= cast_elems) {
            float4 a = *(const float4*)(cf + g);
            float4 c = *(const float4*)(cf + g + 4);
            short8 o;
            o[0] = (short)f2bf(a.x); o[1] = (short)f2bf(a.y);
            o[2] = (short)f2bf(a.z); o[3] = (short)f2bf(a.w);
            o[4] = (short)f2bf(c.x); o[5] = (short)f2bf(c.y);
            o[6] = (short)f2bf(c.z); o[7] = (short)f2bf(c.w);
            *(short8*)(cf16 + g) = o;
        } else {
            for (int i = g; i < cast_elems; ++i) cf16[i] = f2bf(cf[i]);
        }
    } else if (b < castB + startB) {
        int m = (b - castB) * 256 + tid;
        if (m > M) return;
        int prev = (m == 0) ? -1 : seg[m - 1];
        int cur  = (m == M) ? num_cells : seg[m];
        for (int c = prev + 1; c <= cur; ++c) starts[c] = m;
    } else {
        int g = (b - castB - startB) * 256 + tid;   // 0 .. 512*256-1
        if (g < 512 * 256) {
            int n = g >> 8, k = g & 255;
            Wt[g] = f2bf(W[k * 512 + n]);
        }
    }
}

// ---------- kernel 1: segment mean over bf16 table -> cell_emb bf16 ----------
// wave-per-cell. PAIRED gather: one dwordx4 instruction fetches TWO member
// rows (lanes 0-31 -> row A, lanes 32-63 -> row B; 16 B/lane). Lane owns
// features (lane&31)*8..+8; __shfl_xor(.,32) merges even/odd halves at end.
// 8 paired loads (16 members) in flight per batch.
__global__ __launch_bounds__(256) void seg_mean_kernel(
        const unsigned short* __restrict__ cf16,
        const int* __restrict__ member_idx,
        const int* __restrict__ starts,
        int num_cells,
        unsigned short* __restrict__ cell_emb) {
    const int wid  = threadIdx.x >> 6;
    const int lane = threadIdx.x & 63;
    const int half = lane >> 5;          // 0: even member of pair, 1: odd
    const int li   = lane & 31;          // feature group: li*8 .. li*8+7
    const int c = blockIdx.x * 4 + wid;

    float acc[8] = {0.f, 0.f, 0.f, 0.f, 0.f, 0.f, 0.f, 0.f};
    int cnt = 0;

    if (c < num_cells) {
        const int s = starts[c];
        const int e = starts[c + 1];
        cnt = e - s;

        for (int base = s; base < e; base += 64) {
            int m = base + lane;
            int idx = (m < e) ? member_idx[m] : 0;          // coalesced
            int n = e - base; if (n > 64) n = 64;
            int npairs2 = n & ~1;
            for (int j0 = 0; j0 < npairs2; j0 += 16) {      // 8 pairs in flight
                ushort8 v[8];
#pragma unroll
                for (int p = 0; p < 8; ++p) {
                    int jj = j0 + 2 * p;
                    if (jj < npairs2) {
                        int ciA = __shfl(idx, jj);
                        int ciB = __shfl(idx, jj + 1);
                        int ci  = half ? ciB : ciA;
                        v[p] = *(const ushort8*)(cf16 + (size_t)ci * 256 + li * 8);
                    }
                }
#pragma unroll
                for (int p = 0; p < 8; ++p) {
                    int jj = j0 + 2 * p;
                    if (jj < npairs2) {
#pragma unroll
                        for (int t = 0; t < 8; ++t) acc[t] += bf2f(v[p][t]);
                    }
                }
            }
            if (n & 1) {                                    // tail member
                int ci = __shfl(idx, n - 1);
                if (!half) {
                    ushort8 v = *(const ushort8*)(cf16 + (size_t)ci * 256 + li * 8);
#pragma unroll
                    for (int t = 0; t < 8; ++t) acc[t] += bf2f(v[t]);
                }
            }
        }
    }

    // merge even/odd halves, scale, store (lanes 0-31 hold the result)
    float inv = (cnt > 0) ? 1.0f / (float)cnt : 0.f;
    if (c < num_cells && cnt == 0) inv = 0.f;   // zeros out
#pragma unroll
    for (int t = 0; t < 8; ++t)
        acc[t] += __shfl_xor(acc[t], 32);
    if (!half) {
        ushort8 o;
#pragma unroll
        for (int t = 0; t < 8; ++t) o[t] = f2bf(acc[t] * inv);
        *(ushort8*)(cell_emb + (size_t)c * 256 + li * 8) = o;
    }
}

// ---------- kernel 2: C[Mpad x 512] = A[Mpad x 256] * W[256 x 512] + b ----------
__global__ __launch_bounds__(256) void gemm_kernel(
        const unsigned short* __restrict__ A,
        const unsigned short* __restrict__ Bt,
        const float* __restrict__ bias,
        float* __restrict__ out,
        int Mreal) {
    constexpr int LDSS = 40;             // padded stride (bf16 elems)
    __shared__ unsigned short As[128 * LDSS];
    __shared__ unsigned short Bs[128 * LDSS];

    const int tid  = threadIdx.x;
    const int wid  = tid >> 6;
    const int lane = tid & 63;
    const int wm = wid & 1, wn = wid >> 1;
    const int l15 = lane & 15, q = lane >> 4;
    const int m0 = blockIdx.y * 128;
    const int n0 = blockIdx.x * 128;

    floatx4 acc[4][4] = {};

    for (int kb = 0; kb < 256; kb += 32) {
#pragma unroll
        for (int r = 0; r < 2; ++r) {
            int chunk = tid + r * 256;          // 0..511
            int row = chunk >> 2;               // 0..127
            int col = (chunk & 3) * 8;          // 0,8,16,24
            *(short8*)&As[row * LDSS + col] =
                *(const short8*)&A[(size_t)(m0 + row) * 256 + kb + col];
            *(short8*)&Bs[row * LDSS + col] =
                *(const short8*)&Bt[(size_t)(n0 + row) * 256 + kb + col];
        }
        __syncthreads();

        short8 af[4], bf[4];
#pragma unroll
        for (int mi = 0; mi < 4; ++mi)
            af[mi] = *(const short8*)&As[(wm * 64 + mi * 16 + l15) * LDSS + q * 8];
#pragma unroll
        for (int ni = 0; ni < 4; ++ni)
            bf[ni] = *(const short8*)&Bs[(wn * 64 + ni * 16 + l15) * LDSS + q * 8];
#pragma unroll
        for (int mi = 0; mi < 4; ++mi)
#pragma unroll
            for (int ni = 0; ni < 4; ++ni)
                acc[mi][ni] = __builtin_amdgcn_mfma_f32_16x16x32_bf16(
                    af[mi], bf[ni], acc[mi][ni], 0, 0, 0);
        __syncthreads();
    }

#pragma unroll
    for (int ni = 0; ni < 4; ++ni) {
        int n = n0 + wn * 64 + ni * 16 + l15;
        float bv = bias[n];
#pragma unroll
        for (int mi = 0; mi < 4; ++mi) {
            int mbase = m0 + wm * 64 + mi * 16 + q * 4;
#pragma unroll
            for (int r = 0; r < 4; ++r) {
                int row = mbase + r;
                if (row < Mreal)
                    out[(size_t)row * 512 + n] = acc[mi][ni][r] + bv;
            }
        }
    }
}

extern "C" void kernel_launch(void* const* d_in, const int* in_sizes, int n_in,
                              void* d_out, int out_size, void* d_ws, size_t ws_size,
                              hipStream_t stream) {
    const float* chunk_features = (const float*)d_in[0];
    const int*   member_idx     = (const int*)d_in[1];
    const int*   segment_ids    = (const int*)d_in[2];
    const float* W              = (const float*)d_in[4];
    const float* bias           = (const float*)d_in[5];
    float* out = (float*)d_out;

    const int cast_elems = in_sizes[0];          // 100000*256 = 25.6M
    const int M          = in_sizes[1];          // 400000 members
    const int out_dim    = in_sizes[5];          // 512
    const int num_cells  = out_size / out_dim;   // 50000
    const int mtiles = (num_cells + 127) / 128;  // 391
    const int Mpad   = mtiles * 128;             // 50048

    unsigned short* cell_emb = (unsigned short*)d_ws;                 // Mpad*256 bf16
    unsigned short* Wt       = cell_emb + (size_t)Mpad * 256;         // 512*256 bf16
    unsigned short* cf16     = Wt + 512 * 256;                        // cast_elems bf16
    int*            starts   = (int*)(cf16 + (((size_t)cast_elems + 7) & ~7ull)); // num_cells+1

    const int castB  = (cast_elems + 2047) / 2048;   // 8 elems/thread
    const int startB = (M + 1 + 255) / 256;
    const int wtB    = (512 * 256 + 255) / 256;

    hipLaunchKernelGGL(prep_kernel, dim3(castB + startB + wtB), dim3(256), 0, stream,
                       chunk_features, cast_elems, segment_ids, M, num_cells, W,
                       cf16, starts, Wt, castB, startB);
    hipLaunchKernelGGL(seg_mean_kernel, dim3(Mpad / 4), dim3(256), 0, stream,
                       cf16, member_idx, starts, num_cells, cell_emb);
    hipLaunchKernelGGL(gemm_kernel, dim3(4, mtiles), dim3(256), 0, stream,
                       cell_emb, Wt, bias, out, num_cells);
}